// Round 1
// baseline (1502.570 us; speedup 1.0000x reference)
//
#include <hip/hip_runtime.h>
#include <cstdint>
#include <cstddef>

#define IN_F 4096
#define OUT_F 4096
#define MTOT 16384   // 4 * 4096 rows
#define NBLKS 128    // IN_F / 32

typedef __bf16 bf16x8 __attribute__((ext_vector_type(8)));
typedef float f32x4 __attribute__((ext_vector_type(4)));
typedef const __attribute__((address_space(1))) void* gas_cvp;
typedef __attribute__((address_space(3))) void* las_vp;

__device__ __forceinline__ unsigned short f2bf(float f) {
  unsigned u = __builtin_bit_cast(unsigned, f);
  u += 0x7fffu + ((u >> 16) & 1u);   // round-to-nearest-even
  return (unsigned short)(u >> 16);
}

// ---------- Cayley: Q[n] = (I - S)^-1 (I + S),  S = 0.5 (R - R^T) ----------
// One block (1024 threads) per 32x32 block. Gauss-Jordan, no pivoting
// (strictly diagonally dominant: off-diag ~0.007).
__global__ void cayley_kernel(const float* __restrict__ R, float* __restrict__ Q) {
  __shared__ float M[32][66];
  const int n = blockIdx.x;
  const int t = threadIdx.x;
  const int i = t >> 5, j = t & 31;
  const float* Rb = R + n * 1024;
  const float s = 0.5f * (Rb[i * 32 + j] - Rb[j * 32 + i]);
  M[i][j]      = (i == j ? 1.0f : 0.0f) - s;  // A = I - S
  M[i][32 + j] = (i == j ? 1.0f : 0.0f) + s;  // B = I + S
  __syncthreads();
  for (int k = 0; k < 32; ++k) {
    const float pivinv = 1.0f / M[k][k];
    const float fik = M[i][k];
    const float mk1 = M[k][j] * pivinv;
    const float mk2 = M[k][32 + j] * pivinv;
    __syncthreads();
    if (i == k) {
      M[i][j] = mk1;
      M[i][32 + j] = mk2;
    } else {
      M[i][j]      -= fik * mk1;
      M[i][32 + j] -= fik * mk2;
    }
    __syncthreads();
  }
  Q[n * 1024 + i * 32 + j] = M[i][32 + j];   // right half = A^-1 B = Q
}

// ---------- Dequant W[o, g*8+j] = codebooks[0, codes[o,g,0], j] * scales[o] --
// One thread per (o,g); 16B gather from 2MB codebook (L2-resident), 16B store.
__global__ void dequant_kernel(const int* __restrict__ codes,
                               const float* __restrict__ cb,
                               const float* __restrict__ scales,
                               unsigned short* __restrict__ W) {
  const int idx = blockIdx.x * 256 + threadIdx.x;  // o*512 + g
  const int o = idx >> 9;
  const int code = codes[idx];
  const float s = scales[o];
  const float4* cp = (const float4*)(cb + (size_t)code * 8);
  const float4 a = cp[0], b = cp[1];
  uint4 p;
  p.x = (unsigned)f2bf(a.x * s) | ((unsigned)f2bf(a.y * s) << 16);
  p.y = (unsigned)f2bf(a.z * s) | ((unsigned)f2bf(a.w * s) << 16);
  p.z = (unsigned)f2bf(b.x * s) | ((unsigned)f2bf(b.y * s) << 16);
  p.w = (unsigned)f2bf(b.z * s) | ((unsigned)f2bf(b.w * s) << 16);
  ((uint4*)W)[idx] = p;
}

// ---------- Rotate: xr[m, n*32+k] = sum_j x[m, n*32+j] * Q[n][j][k] ---------
// Block = 256 threads: 8 rows x one 32-block. fp32 math, bf16 output.
__global__ void rotate_kernel(const float* __restrict__ x,
                              const float* __restrict__ Q,
                              unsigned short* __restrict__ xr) {
  __shared__ float Qs[1024];
  __shared__ float xs[8][32];
  const int n = blockIdx.y;
  const long m0 = (long)blockIdx.x * 8;
  const int t = threadIdx.x;
#pragma unroll
  for (int i = 0; i < 4; ++i) Qs[t + i * 256] = Q[n * 1024 + t + i * 256];
  const int r = t >> 5, c = t & 31;
  xs[r][c] = x[(m0 + r) * IN_F + n * 32 + c];
  __syncthreads();
  float acc = 0.f;
#pragma unroll
  for (int jj = 0; jj < 32; ++jj) acc += xs[r][jj] * Qs[jj * 32 + c];
  xr[(m0 + r) * IN_F + n * 32 + c] = f2bf(acc);
}

// ---------- GEMM: C[m,n] = sum_k A[m,k] * B[n,k] + bias[n] ------------------
// m97 structure: 128x128 tile, BK=32, 4 waves (2x2), 4x4 16x16x32 MFMA per
// wave, global_load_lds width=16 staging (LDS dest = wave-uniform base +
// lane*16; layout is forced row-major [128][32], no padding).
#define BM 128
#define BN 128
#define BK 32

__global__ __launch_bounds__(256) void gemm_kernel(
    const __bf16* __restrict__ A, const __bf16* __restrict__ B,
    const float* __restrict__ bias, float* __restrict__ C,
    const int M, const int N, const int K) {
  __shared__ __attribute__((aligned(16))) __bf16 As[BM * BK];
  __shared__ __attribute__((aligned(16))) __bf16 Bs[BN * BK];
  const int t = threadIdx.x;
  const int l = t & 63;
  const int w = t >> 6;
  const int wm = w >> 1, wn = w & 1;
  const int lr = l & 15;       // A row-in-16 / B col-in-16
  const int kg = l >> 4;       // k-group: k = kg*8 + j
  const long m0 = (long)blockIdx.y * BM;
  const long n0 = (long)blockIdx.x * BN;

  f32x4 acc[4][4] = {};

  for (int k0 = 0; k0 < K; k0 += BK) {
    // Stage A,B tiles: per wave 2 chunks, chunk c covers LDS elems [c*512, c*512+512)
    // slot s = c*64 + lane -> row = s>>2, koff = (s&3)*8 (contiguous lane order).
#pragma unroll
    for (int q = 0; q < 2; ++q) {
      const int c = w * 2 + q;
      const int s = c * 64 + l;
      const int row = s >> 2;
      const int ko = (s & 3) * 8;
      __builtin_amdgcn_global_load_lds((gas_cvp)(A + (m0 + row) * K + k0 + ko),
                                       (las_vp)(As + c * 512), 16, 0, 0);
      __builtin_amdgcn_global_load_lds((gas_cvp)(B + (n0 + row) * K + k0 + ko),
                                       (las_vp)(Bs + c * 512), 16, 0, 0);
    }
    __syncthreads();

    bf16x8 af[4], bf[4];
#pragma unroll
    for (int i = 0; i < 4; ++i)
      af[i] = *(const bf16x8*)(As + (wm * 64 + i * 16 + lr) * BK + kg * 8);
#pragma unroll
    for (int j = 0; j < 4; ++j)
      bf[j] = *(const bf16x8*)(Bs + (wn * 64 + j * 16 + lr) * BK + kg * 8);
#pragma unroll
    for (int i = 0; i < 4; ++i)
#pragma unroll
      for (int j = 0; j < 4; ++j)
        acc[i][j] = __builtin_amdgcn_mfma_f32_16x16x32_bf16(af[i], bf[j], acc[i][j], 0, 0, 0);
    __syncthreads();
  }

  // Epilogue: D layout col = lane&15, row = (lane>>4)*4 + reg.
#pragma unroll
  for (int j = 0; j < 4; ++j) {
    const long gn = n0 + wn * 64 + j * 16 + lr;
    const float bv = bias[gn];
#pragma unroll
    for (int i = 0; i < 4; ++i) {
#pragma unroll
      for (int r = 0; r < 4; ++r) {
        const long gm = m0 + wm * 64 + i * 16 + kg * 4 + r;
        C[gm * (long)N + gn] = acc[i][j][r] + bv;
      }
    }
  }
}

extern "C" void kernel_launch(void* const* d_in, const int* in_sizes, int n_in,
                              void* d_out, int out_size, void* d_ws, size_t ws_size,
                              hipStream_t stream) {
  const float* x         = (const float*)d_in[0];  // (4,4096,4096) f32
  const float* oft_r     = (const float*)d_in[1];  // (128,32,32) f32
  const int*   codes     = (const int*)d_in[2];    // (4096,512,1) i32
  const float* codebooks = (const float*)d_in[3];  // (1,65536,8) f32
  const float* scales    = (const float*)d_in[4];  // (4096,1) f32
  const float* bias      = (const float*)d_in[5];  // (4096,) f32
  float* out = (float*)d_out;                      // (4,4096,4096) f32

  // Workspace layout (all fully rewritten each launch; poison-safe):
  //   [0, 512KB)            Q fp32   128*32*32
  //   [512KB, 512KB+128MB)  XR bf16  16384*4096
  //   [+32MB)               W  bf16  4096*4096
  char* ws = (char*)d_ws;
  float* Q = (float*)ws;
  unsigned short* XR = (unsigned short*)(ws + (1 << 19));
  unsigned short* W  = (unsigned short*)(ws + (1 << 19) + (size_t)MTOT * IN_F * 2);

  cayley_kernel<<<NBLKS, 1024, 0, stream>>>(oft_r, Q);
  dequant_kernel<<<(OUT_F * (IN_F / 8)) / 256, 256, 0, stream>>>(codes, codebooks, scales, W);
  rotate_kernel<<<dim3(MTOT / 8, NBLKS), 256, 0, stream>>>(x, Q, XR);
  gemm_kernel<<<dim3(OUT_F / BN, MTOT / BM), 256, 0, stream>>>(
      (const __bf16*)XR, (const __bf16*)W, bias, out, MTOT, OUT_F, IN_F);
}

// Round 2
// 1279.361 us; speedup vs baseline: 1.1745x; 1.1745x over previous
//
#include <hip/hip_runtime.h>
#include <cstdint>
#include <cstddef>

#define IN_F 4096
#define OUT_F 4096
#define MTOT 16384   // 4 * 4096 rows
#define NBLKS 128    // IN_F / 32

typedef __bf16 bf16x8 __attribute__((ext_vector_type(8)));
typedef float f32x4 __attribute__((ext_vector_type(4)));
typedef const __attribute__((address_space(1))) void* gas_cvp;
typedef __attribute__((address_space(3))) void* las_vp;

__device__ __forceinline__ unsigned short f2bf(float f) {
  unsigned u = __builtin_bit_cast(unsigned, f);
  u += 0x7fffu + ((u >> 16) & 1u);   // round-to-nearest-even
  return (unsigned short)(u >> 16);
}

// ---------- Cayley: Q[n] = (I - S)^-1 (I + S),  S = 0.5 (R - R^T) ----------
__global__ void cayley_kernel(const float* __restrict__ R, float* __restrict__ Q) {
  __shared__ float M[32][66];
  const int n = blockIdx.x;
  const int t = threadIdx.x;
  const int i = t >> 5, j = t & 31;
  const float* Rb = R + n * 1024;
  const float s = 0.5f * (Rb[i * 32 + j] - Rb[j * 32 + i]);
  M[i][j]      = (i == j ? 1.0f : 0.0f) - s;  // A = I - S
  M[i][32 + j] = (i == j ? 1.0f : 0.0f) + s;  // B = I + S
  __syncthreads();
  for (int k = 0; k < 32; ++k) {
    const float pivinv = 1.0f / M[k][k];
    const float fik = M[i][k];
    const float mk1 = M[k][j] * pivinv;
    const float mk2 = M[k][32 + j] * pivinv;
    __syncthreads();
    if (i == k) {
      M[i][j] = mk1;
      M[i][32 + j] = mk2;
    } else {
      M[i][j]      -= fik * mk1;
      M[i][32 + j] -= fik * mk2;
    }
    __syncthreads();
  }
  Q[n * 1024 + i * 32 + j] = M[i][32 + j];
}

// ---------- Dequant W[o, g*8+j] = codebooks[0, codes[o,g,0], j] * scales[o] --
__global__ void dequant_kernel(const int* __restrict__ codes,
                               const float* __restrict__ cb,
                               const float* __restrict__ scales,
                               unsigned short* __restrict__ W) {
  const int idx = blockIdx.x * 256 + threadIdx.x;  // o*512 + g
  const int o = idx >> 9;
  const int code = codes[idx];
  const float s = scales[o];
  const float4* cp = (const float4*)(cb + (size_t)code * 8);
  const float4 a = cp[0], b = cp[1];
  uint4 p;
  p.x = (unsigned)f2bf(a.x * s) | ((unsigned)f2bf(a.y * s) << 16);
  p.y = (unsigned)f2bf(a.z * s) | ((unsigned)f2bf(a.w * s) << 16);
  p.z = (unsigned)f2bf(b.x * s) | ((unsigned)f2bf(b.y * s) << 16);
  p.w = (unsigned)f2bf(b.z * s) | ((unsigned)f2bf(b.w * s) << 16);
  ((uint4*)W)[idx] = p;
}

// ---------- Rotate: xr[m, n*32+c] = sum_j x[m, n*32+j] * Q[n][j][c] ---------
// One thread per (row m, n-block): 256 threads/block = 256 rows, grid (64,128).
// Q broadcast from LDS (uniform-address b128 reads, conflict-free); x via
// float4; 32 bf16 outputs packed into 4 uint4 stores.
__global__ __launch_bounds__(256) void rotate_kernel(
    const float* __restrict__ x, const float* __restrict__ Q,
    unsigned short* __restrict__ xr) {
  __shared__ float Qs[1024];
  const int n = blockIdx.y;
  const int t = threadIdx.x;
#pragma unroll
  for (int i = 0; i < 4; ++i) Qs[t + i * 256] = Q[n * 1024 + t + i * 256];
  __syncthreads();
  const long m = (long)blockIdx.x * 256 + t;
  const float4* xp = (const float4*)(x + m * IN_F + n * 32);
  float4 xv[8];
#pragma unroll
  for (int j4 = 0; j4 < 8; ++j4) xv[j4] = xp[j4];
  float4 acc[8] = {};
  const float* xs = (const float*)xv;
#pragma unroll
  for (int j = 0; j < 32; ++j) {
    const float xj = xs[j];
#pragma unroll
    for (int c4 = 0; c4 < 8; ++c4) {
      const float4 q = ((const float4*)Qs)[j * 8 + c4];
      acc[c4].x += xj * q.x;
      acc[c4].y += xj * q.y;
      acc[c4].z += xj * q.z;
      acc[c4].w += xj * q.w;
    }
  }
  uint4* op = (uint4*)(xr + m * IN_F + n * 32);
#pragma unroll
  for (int g = 0; g < 4; ++g) {
    const float4 a = acc[2 * g], b = acc[2 * g + 1];
    uint4 p;
    p.x = (unsigned)f2bf(a.x) | ((unsigned)f2bf(a.y) << 16);
    p.y = (unsigned)f2bf(a.z) | ((unsigned)f2bf(a.w) << 16);
    p.z = (unsigned)f2bf(b.x) | ((unsigned)f2bf(b.y) << 16);
    p.w = (unsigned)f2bf(b.z) | ((unsigned)f2bf(b.w) << 16);
    op[g] = p;
  }
}

// ---------- GEMM: C[m,n] = sum_k A[m,k] * B[n,k] + bias[n] ------------------
// 128x128 tile, BK=64 (32 MFMA per barrier), 4 waves (2x2), 4x4 16x16x32 MFMA.
// LDS layout XOR-swizzled at 16B granularity: row r's k-chunk c lives at slot
// r*8 + (c ^ (r&7)). Staging source permutes chunks within the same 128B row
// segment (coalescing unchanged); fragment ds_read_b128 then hits 8 distinct
// bank-groups with only free 2-way aliasing (m136).
#define BM 128
#define BN 128
#define BK 64

__global__ __launch_bounds__(256) void gemm_kernel(
    const __bf16* __restrict__ A, const __bf16* __restrict__ B,
    const float* __restrict__ bias, float* __restrict__ C,
    const int M, const int N, const int K) {
  __shared__ __attribute__((aligned(16))) __bf16 As[BM * BK];
  __shared__ __attribute__((aligned(16))) __bf16 Bs[BN * BK];
  const int t = threadIdx.x;
  const int l = t & 63;
  const int w = t >> 6;
  const int wm = w >> 1, wn = w & 1;
  const int lr = l & 15;       // row-in-16
  const int kg = l >> 4;       // k-subgroup within 32-elem MFMA K
  const long m0 = (long)blockIdx.y * BM;
  const long n0 = (long)blockIdx.x * BN;

  // Staging lane offsets (K-invariant): instr q covers LDS slots
  // [(w*4+q)*64, +64); slot s -> row = s>>3, lds-chunk j = s&7,
  // source chunk = j ^ (row&7).
  int off[4];
#pragma unroll
  for (int q = 0; q < 4; ++q) {
    const int s = (w * 4 + q) * 64 + l;
    const int row = s >> 3;
    const int csrc = (s & 7) ^ (row & 7);
    off[q] = row * K + csrc * 8;
  }

  f32x4 acc[4][4] = {};

  for (int k0 = 0; k0 < K; k0 += BK) {
    const __bf16* Ab = A + m0 * K + k0;
    const __bf16* Bb = B + n0 * K + k0;
#pragma unroll
    for (int q = 0; q < 4; ++q) {
      __builtin_amdgcn_global_load_lds((gas_cvp)(Ab + off[q]),
                                       (las_vp)(As + (w * 4 + q) * 512), 16, 0, 0);
      __builtin_amdgcn_global_load_lds((gas_cvp)(Bb + off[q]),
                                       (las_vp)(Bs + (w * 4 + q) * 512), 16, 0, 0);
    }
    __syncthreads();

#pragma unroll
    for (int kk = 0; kk < 2; ++kk) {
      bf16x8 af[4], bf[4];
      const int cc = kk * 4 + kg;
      const int jl = cc ^ (lr & 7);   // swizzled 16B chunk within row
#pragma unroll
      for (int i = 0; i < 4; ++i) {
        const int r = wm * 64 + i * 16 + lr;
        af[i] = *(const bf16x8*)(As + r * BK + jl * 8);
      }
#pragma unroll
      for (int j = 0; j < 4; ++j) {
        const int r = wn * 64 + j * 16 + lr;
        bf[j] = *(const bf16x8*)(Bs + r * BK + jl * 8);
      }
#pragma unroll
      for (int i = 0; i < 4; ++i)
#pragma unroll
        for (int j = 0; j < 4; ++j)
          acc[i][j] = __builtin_amdgcn_mfma_f32_16x16x32_bf16(af[i], bf[j], acc[i][j], 0, 0, 0);
    }
    __syncthreads();
  }

  // Epilogue: D layout col = lane&15, row = (lane>>4)*4 + reg.
#pragma unroll
  for (int j = 0; j < 4; ++j) {
    const long gn = n0 + wn * 64 + j * 16 + lr;
    const float bv = bias[gn];
#pragma unroll
    for (int i = 0; i < 4; ++i) {
#pragma unroll
      for (int r = 0; r < 4; ++r) {
        const long gm = m0 + wm * 64 + i * 16 + kg * 4 + r;
        C[gm * (long)N + gn] = acc[i][j][r] + bv;
      }
    }
  }
}

extern "C" void kernel_launch(void* const* d_in, const int* in_sizes, int n_in,
                              void* d_out, int out_size, void* d_ws, size_t ws_size,
                              hipStream_t stream) {
  const float* x         = (const float*)d_in[0];  // (4,4096,4096) f32
  const float* oft_r     = (const float*)d_in[1];  // (128,32,32) f32
  const int*   codes     = (const int*)d_in[2];    // (4096,512,1) i32
  const float* codebooks = (const float*)d_in[3];  // (1,65536,8) f32
  const float* scales    = (const float*)d_in[4];  // (4096,1) f32
  const float* bias      = (const float*)d_in[5];  // (4096,) f32
  float* out = (float*)d_out;                      // (4,4096,4096) f32

  char* ws = (char*)d_ws;
  float* Q = (float*)ws;                                   // 512 KB
  unsigned short* XR = (unsigned short*)(ws + (1 << 19));  // 128 MB bf16
  unsigned short* W  = (unsigned short*)(ws + (1 << 19) + (size_t)MTOT * IN_F * 2);  // 32 MB

  cayley_kernel<<<NBLKS, 1024, 0, stream>>>(oft_r, Q);
  dequant_kernel<<<(OUT_F * (IN_F / 8)) / 256, 256, 0, stream>>>(codes, codebooks, scales, W);
  rotate_kernel<<<dim3(MTOT / 256, NBLKS), 256, 0, stream>>>(x, Q, XR);
  gemm_kernel<<<dim3(OUT_F / BN, MTOT / BM), 256, 0, stream>>>(
      (const __bf16*)XR, (const __bf16*)W, bias, out, MTOT, OUT_F, IN_F);
}